// Round 4
// baseline (42.769 us; speedup 1.0000x reference)
//
#include <hip/hip_runtime.h>
#include <stdint.h>

#define NANCH   8192
#define NCLS    80
#define NCHUNK  128            // 8192 / 64
#define IMW     1024
#define IMH     1024
#define MAXDET  100
#define SCORE_TH 0.05f
#define STAGE_R 8              // staged ranks per chunk (top-8, guard = 9th)
#define NRUN    16             // Phase-A runs per batch
#define NSEL    256            // Phase-B selected candidates (top-16 per run)

// key layout: [63:32] monotonic(score) | [31:16] ~anchor_idx (stable tie-break) | [15:0] class
// meta layout: 4 x int16 box coords (x1,y1,x2,y2)
__device__ __forceinline__ float key_score(uint64_t key) {
    uint32_t m = (uint32_t)(key >> 32);
    uint32_t bits = (m & 0x80000000u) ? (m & 0x7FFFFFFFu) : ~m;
    return __uint_as_float(bits);
}

// ---------------- Kernel 1: decode + per-wave 64-chunk register sort ----------------
__global__ __launch_bounds__(64)
void decode_sort_kernel(const float* __restrict__ cls_heads,
                        const float* __restrict__ reg_heads,
                        const float* __restrict__ anchors,
                        uint64_t* __restrict__ ws) {
    const int lane  = threadIdx.x;
    const int chunk = blockIdx.x;
    const int b     = blockIdx.y;
    const int n     = chunk * 64 + lane;
    const int row   = b * NANCH + n;

    const float4* cp = reinterpret_cast<const float4*>(cls_heads + (size_t)row * NCLS);
    float best = -1e30f; int bestj = 0;
#pragma unroll
    for (int k = 0; k < NCLS / 4; ++k) {
        float4 v = cp[k];
        if (v.x > best) { best = v.x; bestj = 4 * k + 0; }
        if (v.y > best) { best = v.y; bestj = 4 * k + 1; }
        if (v.z > best) { best = v.z; bestj = 4 * k + 2; }
        if (v.w > best) { best = v.w; bestj = 4 * k + 3; }
    }

    float4 r = reinterpret_cast<const float4*>(reg_heads)[row];
    float4 a = reinterpret_cast<const float4*>(anchors)[row];

    // decode — _rn intrinsics block fma contraction (trunc boundaries ulp-sensitive)
    float awx = __fsub_rn(a.z, a.x);
    float awy = __fsub_rn(a.w, a.y);
    float acx = __fadd_rn(a.x, __fmul_rn(0.5f, awx));
    float acy = __fadd_rn(a.y, __fmul_rn(0.5f, awy));
    float rx = __fmul_rn(r.x, 0.1f);
    float ry = __fmul_rn(r.y, 0.1f);
    float rw = __fmul_rn(r.z, 0.2f);
    float rh = __fmul_rn(r.w, 0.2f);
    float pwx = __fmul_rn(expf(rw), awx);
    float pwy = __fmul_rn(expf(rh), awy);
    float pcx = __fadd_rn(__fmul_rn(rx, awx), acx);
    float pcy = __fadd_rn(__fmul_rn(ry, awy), acy);

    int x1 = (int)__fsub_rn(pcx, __fmul_rn(0.5f, pwx));
    int y1 = (int)__fsub_rn(pcy, __fmul_rn(0.5f, pwy));
    int x2 = (int)__fadd_rn(pcx, __fmul_rn(0.5f, pwx));
    int y2 = (int)__fadd_rn(pcy, __fmul_rn(0.5f, pwy));
    x1 = max(x1, 0);
    y1 = max(y1, 0);
    x2 = min(x2, IMW - 1);
    y2 = min(y2, IMH - 1);

    uint32_t u = __float_as_uint(best);
    uint32_t mono = (u & 0x80000000u) ? ~u : (u | 0x80000000u);
    uint64_t key = ((uint64_t)mono << 32)
                 | ((uint64_t)((~(uint32_t)n) & 0xFFFFu) << 16)
                 | (uint64_t)(uint32_t)bestj;
    uint64_t meta = (uint64_t)(uint16_t)x1
                  | ((uint64_t)(uint16_t)y1 << 16)
                  | ((uint64_t)(uint16_t)x2 << 32)
                  | ((uint64_t)(uint16_t)y2 << 48);

    // descending bitonic sort across 64 lanes, registers only
#pragma unroll
    for (int k = 2; k <= 64; k <<= 1) {
#pragma unroll
        for (int j = k >> 1; j > 0; j >>= 1) {
            uint64_t ok = __shfl_xor(key, j);
            uint64_t om = __shfl_xor(meta, j);
            bool keepmin = (((lane & k) != 0) == ((lane & j) == 0));
            bool take = keepmin ? (ok < key) : (ok > key);
            if (take) { key = ok; meta = om; }
        }
    }

    size_t pos = ((size_t)b * NCHUNK + chunk) * 64 + lane;
    ws[2 * pos]     = key;
    ws[2 * pos + 1] = meta;
}

// ---------------- fallback helpers (cold path, exact) ----------------
struct Kept {
    float x1[2], y1[2], x2[2], y2[2], ar[2];
    int   cl[2];
};

__device__ __forceinline__ void nms_try_keep(uint64_t key, uint64_t meta, float s,
                                             int lane, int& nk, Kept& K,
                                             float* __restrict__ out, int b) {
    int cls = (int)(key & 0xFFFFu);
    float cx1 = (float)(short)(meta & 0xFFFFu);
    float cy1 = (float)(short)((meta >> 16) & 0xFFFFu);
    float cx2 = (float)(short)((meta >> 32) & 0xFFFFu);
    float cy2 = (float)(short)((meta >> 48) & 0xFFFFu);
    float ca = fmaxf(cx2 - cx1, 0.f) * fmaxf(cy2 - cy1, 0.f);

    bool supp = false;
#pragma unroll
    for (int r = 0; r < 2; ++r) {
        int slot = lane + 64 * r;
        if (slot < nk && K.cl[r] == cls) {
            float ix1 = fmaxf(K.x1[r], cx1), iy1 = fmaxf(K.y1[r], cy1);
            float ix2 = fminf(K.x2[r], cx2), iy2 = fminf(K.y2[r], cy2);
            float inter = fmaxf(ix2 - ix1, 0.f) * fmaxf(iy2 - iy1, 0.f);
            if (3.f * inter > K.ar[r] + ca) supp = true;   // exact iou>0.5 (ints exact in f32)
        }
    }
    if (__ballot(supp) != 0ULL) return;

    int rr = nk >> 6, l = nk & 63;
    if (lane == l) {
        if (rr == 0) { K.x1[0]=cx1; K.y1[0]=cy1; K.x2[0]=cx2; K.y2[0]=cy2; K.ar[0]=ca; K.cl[0]=cls; }
        else         { K.x1[1]=cx1; K.y1[1]=cy1; K.x2[1]=cx2; K.y2[1]=cy2; K.ar[1]=ca; K.cl[1]=cls; }
    }
    if (lane == 0) {
        out[b * MAXDET + nk] = s;
        out[2 * MAXDET + b * MAXDET + nk] = (float)cls;
        float* ob = out + 4 * MAXDET + (size_t)(b * MAXDET + nk) * 4;
        ob[0] = cx1; ob[1] = cy1; ob[2] = cx2; ob[3] = cy2;
    }
    ++nk;
}

// ---------------- Kernel 2: 2-level select + register sort-256 + batched NMS ----------------
__global__ __launch_bounds__(1024)
void sort_nms_kernel(const uint64_t* __restrict__ ws, float* __restrict__ out) {
    __shared__ __align__(16) uint64_t sp[2 * NRUN * 64];   // 16 sorted runs of 64 (key,meta)
    __shared__ __align__(16) uint64_t sq[2 * NSEL];        // sorted 256 for NMS
    __shared__ uint64_t karr[NCHUNK];
    __shared__ float4 kept_box[MAXDET];
    __shared__ float  kept_area[MAXDET];
    __shared__ int    kept_cls[MAXDET];

    const int b = blockIdx.x;
    const int tid = threadIdx.x;
    const int w = tid >> 6;
    const int lane = tid & 63;
    const uint64_t* g = ws + (size_t)b * NCHUNK * 64 * 2;

    // ---- Phase A: each wave register-sorts its 64 staged entries (top-8 of 8 chunks) ----
    {
        int chunk = w * 8 + (lane >> 3), rank = lane & 7;
        size_t e = (size_t)chunk * 64 + rank;
        uint64_t rk = g[2 * e];
        uint64_t rm = g[2 * e + 1];
        if (tid < NCHUNK) karr[tid] = g[2 * ((size_t)tid * 64 + STAGE_R)];  // 9th-best per chunk

#pragma unroll
        for (int k = 2; k <= 64; k <<= 1) {
#pragma unroll
            for (int j = k >> 1; j > 0; j >>= 1) {
                uint64_t ok = __shfl_xor(rk, j);
                uint64_t om = __shfl_xor(rm, j);
                bool keepmin = (((lane & k) != 0) == ((lane & j) == 0));
                bool take = keepmin ? (ok < rk) : (ok > rk);
                if (take) { rk = ok; rm = om; }
            }
        }
        *reinterpret_cast<ulonglong2*>(&sp[2 * (w * 64 + lane)]) = make_ulonglong2(rk, rm);
    }
    __syncthreads();

    if (tid >= 64) return;

    // ---- wave 0 from here on (no barriers needed) ----
    // guards
    uint64_t kstar;
    {
        uint64_t m = karr[lane] > karr[lane + 64] ? karr[lane] : karr[lane + 64];
        uint64_t m2 = (lane < NRUN) ? sp[2 * (lane * 64 + 16)] : 0ULL;  // 17th of each run
        if (m2 > m) m = m2;
#pragma unroll
        for (int j = 32; j; j >>= 1) {
            uint64_t o = __shfl_xor(m, j);
            if (o > m) m = o;
        }
        kstar = m;
    }

    // load top-16 of each run: position p = i*64+lane, run = p>>4, rank = p&15
    uint64_t k4[4], m4[4];
#pragma unroll
    for (int i = 0; i < 4; ++i) {
        int p = i * 64 + lane;
        ulonglong2 v = *reinterpret_cast<const ulonglong2*>(&sp[2 * ((p >> 4) * 64 + (p & 15))]);
        k4[i] = v.x; m4[i] = v.y;
    }

    // full bitonic sort-256 descending over p = i*64+lane (j>=64 stages are intra-lane reg swaps)
    for (int k = 2; k <= NSEL; k <<= 1) {
        for (int j = k >> 1; j > 0; j >>= 1) {
            if (j >= 64) {
                int d = j >> 6;
#pragma unroll
                for (int i = 0; i < 4; ++i) {
                    if (!(i & d)) {
                        int ih = i | d;
                        int p_il = i * 64 + lane;
                        bool ilmin = ((p_il & k) != 0);
                        bool sw = ilmin ? (k4[i] > k4[ih]) : (k4[i] < k4[ih]);
                        if (sw) {
                            uint64_t tk = k4[i]; k4[i] = k4[ih]; k4[ih] = tk;
                            uint64_t tm = m4[i]; m4[i] = m4[ih]; m4[ih] = tm;
                        }
                    }
                }
            } else {
#pragma unroll
                for (int i = 0; i < 4; ++i) {
                    int p = i * 64 + lane;
                    uint64_t ok = __shfl_xor(k4[i], j);
                    uint64_t om = __shfl_xor(m4[i], j);
                    bool keepmin = (((p & k) != 0) == ((lane & j) == 0));
                    bool take = keepmin ? (ok < k4[i]) : (ok > k4[i]);
                    if (take) { k4[i] = ok; m4[i] = om; }
                }
            }
        }
    }

#pragma unroll
    for (int i = 0; i < 4; ++i)
        *reinterpret_cast<ulonglong2*>(&sq[2 * (i * 64 + lane)]) = make_ulonglong2(k4[i], m4[i]);

    // ---- batched greedy NMS over sorted 256 ----
    int nk = 0;
    bool need_fb = false;
    bool done = false;

    for (int p0 = 0; p0 < NSEL && !done; p0 += 64) {
        ulonglong2 kv = *reinterpret_cast<const ulonglong2*>(&sq[2 * (p0 + lane)]);
        uint64_t key = kv.x, meta = kv.y;
        float s = key_score(key);
        int cls = (int)(key & 0xFFFFu);
        float cx1 = (float)(short)(meta & 0xFFFFu);
        float cy1 = (float)(short)((meta >> 16) & 0xFFFFu);
        float cx2 = (float)(short)((meta >> 32) & 0xFFFFu);
        float cy2 = (float)(short)((meta >> 48) & 0xFFFFu);
        float ca = fmaxf(cx2 - cx1, 0.f) * fmaxf(cy2 - cy1, 0.f);
        bool sval = (s > SCORE_TH);
        bool trusted = (key > kstar);

        // vs previously-kept set (LDS broadcast reads)
        bool supk = false;
        for (int j = 0; j < nk; ++j) {
            float4 kb = kept_box[j];
            float ix1 = fmaxf(kb.x, cx1), iy1 = fmaxf(kb.y, cy1);
            float ix2 = fminf(kb.z, cx2), iy2 = fminf(kb.w, cy2);
            float inter = fmaxf(ix2 - ix1, 0.f) * fmaxf(iy2 - iy1, 0.f);
            supk |= (kept_cls[j] == cls) & (3.f * inter > kept_area[j] + ca);
        }
        bool alive0 = sval && trusted && !supk;

        // intra-batch pairwise suppression mask (broadcast LDS reads)
        uint64_t supBy = 0;
#pragma unroll 4
        for (int t = 0; t < 64; ++t) {
            ulonglong2 tv = *reinterpret_cast<const ulonglong2*>(&sq[2 * (p0 + t)]);
            uint64_t tkey = tv.x, tmeta = tv.y;
            float ts = key_score(tkey);
            int tcls = (int)(tkey & 0xFFFFu);
            float tx1 = (float)(short)(tmeta & 0xFFFFu);
            float ty1 = (float)(short)((tmeta >> 16) & 0xFFFFu);
            float tx2 = (float)(short)((tmeta >> 32) & 0xFFFFu);
            float ty2 = (float)(short)((tmeta >> 48) & 0xFFFFu);
            float ta = fmaxf(tx2 - tx1, 0.f) * fmaxf(ty2 - ty1, 0.f);
            float ix1 = fmaxf(tx1, cx1), iy1 = fmaxf(ty1, cy1);
            float ix2 = fminf(tx2, cx2), iy2 = fminf(ty2, cy2);
            float inter = fmaxf(ix2 - ix1, 0.f) * fmaxf(iy2 - iy1, 0.f);
            bool sup = (t < lane) && (ts > SCORE_TH) && (tcls == cls)
                       && (3.f * inter > ta + ca);
            supBy |= ((uint64_t)sup) << t;
        }

        uint64_t aliveCand = __ballot(alive0);
        uint64_t aliveMask;
        if (__ballot(supBy != 0ULL) == 0ULL) {
            aliveMask = aliveCand;          // fast path: no intra-batch suppression at all
        } else {
            uint64_t killed = 0;
            for (int t = 0; t < 64; ++t) {
                uint64_t kill_t = __ballot((supBy >> t) & 1ULL);
                bool talive = ((aliveCand >> t) & 1ULL) && !((killed >> t) & 1ULL);
                if (talive) killed |= kill_t;
            }
            aliveMask = aliveCand & ~killed;
        }

        int myrank = __popcll(aliveMask & ((1ULL << lane) - 1ULL));
        bool keepme = ((aliveMask >> lane) & 1ULL) && (nk + myrank < MAXDET);
        if (keepme) {
            int slot = nk + myrank;
            kept_box[slot]  = make_float4(cx1, cy1, cx2, cy2);
            kept_area[slot] = ca;
            kept_cls[slot]  = cls;
            out[b * MAXDET + slot] = s;
            out[2 * MAXDET + b * MAXDET + slot] = (float)cls;
            float* ob = out + 4 * MAXDET + (size_t)(b * MAXDET + slot) * 4;
            ob[0] = cx1; ob[1] = cy1; ob[2] = cx2; ob[3] = cy2;
        }
        int navail = __popcll(aliveMask);
        int room = MAXDET - nk;
        nk += (navail < room) ? navail : room;

        uint64_t guardFail = __ballot(sval && !trusted);
        uint64_t invalid   = __ballot(!sval);
        if (nk >= MAXDET) done = true;
        else if (guardFail) { need_fb = true; done = true; }
        else if (invalid) done = true;
    }
    if (!done && nk < MAXDET) need_fb = true;   // exhausted selected set

    // ---- cold exact fallback: 128-stream merge over full sorted chunks ----
    if (need_fb) {
        nk = 0;
        Kept K;
        K.cl[0] = K.cl[1] = -1;
        K.x1[0]=K.y1[0]=K.x2[0]=K.y2[0]=K.ar[0]=0.f;
        K.x1[1]=K.y1[1]=K.x2[1]=K.y2[1]=K.ar[1]=0.f;
        int p0 = 0, p1 = 0;
        uint64_t h0k = g[2 * ((size_t)lane * 64)];
        uint64_t h0m = g[2 * ((size_t)lane * 64) + 1];
        uint64_t h1k = g[2 * ((size_t)(lane + 64) * 64)];
        uint64_t h1m = g[2 * ((size_t)(lane + 64) * 64) + 1];
        while (true) {
            uint64_t mk = (h0k > h1k) ? h0k : h1k;
            uint64_t r = mk;
#pragma unroll
            for (int j = 32; j; j >>= 1) {
                uint64_t o = __shfl_xor(r, j);
                if (o > r) r = o;
            }
            if (r == 0ULL) break;
            float s = key_score(r);
            if (!(s > SCORE_TH)) break;
            uint64_t wmask = __ballot(mk == r);
            int wl = __ffsll((unsigned long long)wmask) - 1;
            uint64_t mym = (h0k > h1k) ? h0m : h1m;
            uint64_t cm = __shfl(mym, wl);
            nms_try_keep(r, cm, s, lane, nk, K, out, b);
            if (nk == MAXDET) break;
            if (lane == wl) {
                if (h0k > h1k) {
                    ++p0; bool v = p0 < 64;
                    h0k = v ? g[2 * ((size_t)lane * 64 + p0)] : 0ULL;
                    h0m = v ? g[2 * ((size_t)lane * 64 + p0) + 1] : 0ULL;
                } else {
                    ++p1; bool v = p1 < 64;
                    h1k = v ? g[2 * ((size_t)(lane + 64) * 64 + p1)] : 0ULL;
                    h1m = v ? g[2 * ((size_t)(lane + 64) * 64 + p1) + 1] : 0ULL;
                }
            }
        }
    }

    // pad remaining slots with -1
    for (int t = nk + lane; t < MAXDET; t += 64) {
        out[b * MAXDET + t] = -1.f;
        out[2 * MAXDET + b * MAXDET + t] = -1.f;
        float* ob = out + 4 * MAXDET + (size_t)(b * MAXDET + t) * 4;
        ob[0] = -1.f; ob[1] = -1.f; ob[2] = -1.f; ob[3] = -1.f;
    }
}

extern "C" void kernel_launch(void* const* d_in, const int* in_sizes, int n_in,
                              void* d_out, int out_size, void* d_ws, size_t ws_size,
                              hipStream_t stream) {
    (void)in_sizes; (void)n_in; (void)out_size; (void)ws_size;
    const float* cls_heads = (const float*)d_in[0];
    const float* reg_heads = (const float*)d_in[1];
    const float* anchors   = (const float*)d_in[2];
    float* out = (float*)d_out;
    uint64_t* ws = (uint64_t*)d_ws;   // 2 batches x 128 chunks x 64 x (key,meta) = 256 KiB

    decode_sort_kernel<<<dim3(NCHUNK, 2), 64, 0, stream>>>(cls_heads, reg_heads, anchors, ws);
    sort_nms_kernel<<<dim3(2), 1024, 0, stream>>>(ws, out);
}

// Round 5
// 32.684 us; speedup vs baseline: 1.3086x; 1.3086x over previous
//
#include <hip/hip_runtime.h>
#include <stdint.h>

#define NANCH   8192
#define NCLS    80
#define NCHUNK  128            // 8192 / 64
#define IMW     1024
#define IMH     1024
#define MAXDET  100
#define SCORE_TH 0.05f
#define STAGE_R 8              // staged ranks per chunk (top-8, guard = 9th)
#define NRUN    16             // Phase-A runs per batch
#define NSEL    256            // Phase-B selected candidates (top-16 per run)

// key layout: [63:32] monotonic(score) | [31:16] ~anchor_idx (stable tie-break) | [15:0] class
// meta layout: 4 x int16 box coords (x1,y1,x2,y2)
__device__ __forceinline__ float key_score(uint64_t key) {
    uint32_t m = (uint32_t)(key >> 32);
    uint32_t bits = (m & 0x80000000u) ? (m & 0x7FFFFFFFu) : ~m;
    return __uint_as_float(bits);
}

// ---------------- Kernel 1: decode + per-wave 64-chunk register sort ----------------
__global__ __launch_bounds__(64)
void decode_sort_kernel(const float* __restrict__ cls_heads,
                        const float* __restrict__ reg_heads,
                        const float* __restrict__ anchors,
                        uint64_t* __restrict__ ws) {
    const int lane  = threadIdx.x;
    const int chunk = blockIdx.x;
    const int b     = blockIdx.y;
    const int n     = chunk * 64 + lane;
    const int row   = b * NANCH + n;

    const float4* cp = reinterpret_cast<const float4*>(cls_heads + (size_t)row * NCLS);
    float best = -1e30f; int bestj = 0;
#pragma unroll
    for (int k = 0; k < NCLS / 4; ++k) {
        float4 v = cp[k];
        if (v.x > best) { best = v.x; bestj = 4 * k + 0; }
        if (v.y > best) { best = v.y; bestj = 4 * k + 1; }
        if (v.z > best) { best = v.z; bestj = 4 * k + 2; }
        if (v.w > best) { best = v.w; bestj = 4 * k + 3; }
    }

    float4 r = reinterpret_cast<const float4*>(reg_heads)[row];
    float4 a = reinterpret_cast<const float4*>(anchors)[row];

    // decode — _rn intrinsics block fma contraction (trunc boundaries ulp-sensitive)
    float awx = __fsub_rn(a.z, a.x);
    float awy = __fsub_rn(a.w, a.y);
    float acx = __fadd_rn(a.x, __fmul_rn(0.5f, awx));
    float acy = __fadd_rn(a.y, __fmul_rn(0.5f, awy));
    float rx = __fmul_rn(r.x, 0.1f);
    float ry = __fmul_rn(r.y, 0.1f);
    float rw = __fmul_rn(r.z, 0.2f);
    float rh = __fmul_rn(r.w, 0.2f);
    float pwx = __fmul_rn(expf(rw), awx);
    float pwy = __fmul_rn(expf(rh), awy);
    float pcx = __fadd_rn(__fmul_rn(rx, awx), acx);
    float pcy = __fadd_rn(__fmul_rn(ry, awy), acy);

    int x1 = (int)__fsub_rn(pcx, __fmul_rn(0.5f, pwx));
    int y1 = (int)__fsub_rn(pcy, __fmul_rn(0.5f, pwy));
    int x2 = (int)__fadd_rn(pcx, __fmul_rn(0.5f, pwx));
    int y2 = (int)__fadd_rn(pcy, __fmul_rn(0.5f, pwy));
    x1 = max(x1, 0);
    y1 = max(y1, 0);
    x2 = min(x2, IMW - 1);
    y2 = min(y2, IMH - 1);

    uint32_t u = __float_as_uint(best);
    uint32_t mono = (u & 0x80000000u) ? ~u : (u | 0x80000000u);
    uint64_t key = ((uint64_t)mono << 32)
                 | ((uint64_t)((~(uint32_t)n) & 0xFFFFu) << 16)
                 | (uint64_t)(uint32_t)bestj;
    uint64_t meta = (uint64_t)(uint16_t)x1
                  | ((uint64_t)(uint16_t)y1 << 16)
                  | ((uint64_t)(uint16_t)x2 << 32)
                  | ((uint64_t)(uint16_t)y2 << 48);

    // descending bitonic sort across 64 lanes, registers only
#pragma unroll
    for (int k = 2; k <= 64; k <<= 1) {
#pragma unroll
        for (int j = k >> 1; j > 0; j >>= 1) {
            uint64_t ok = __shfl_xor(key, j);
            uint64_t om = __shfl_xor(meta, j);
            bool keepmin = (((lane & k) != 0) == ((lane & j) == 0));
            bool take = keepmin ? (ok < key) : (ok > key);
            if (take) { key = ok; meta = om; }
        }
    }

    size_t pos = ((size_t)b * NCHUNK + chunk) * 64 + lane;
    ws[2 * pos]     = key;
    ws[2 * pos + 1] = meta;
}

// ---------------- fallback helpers (cold path, exact) ----------------
struct Kept {
    float x1[2], y1[2], x2[2], y2[2], ar[2];
    int   cl[2];
};

__device__ __forceinline__ void nms_try_keep(uint64_t key, uint64_t meta, float s,
                                             int lane, int& nk, Kept& K,
                                             float* __restrict__ out, int b) {
    int cls = (int)(key & 0xFFFFu);
    float cx1 = (float)(short)(meta & 0xFFFFu);
    float cy1 = (float)(short)((meta >> 16) & 0xFFFFu);
    float cx2 = (float)(short)((meta >> 32) & 0xFFFFu);
    float cy2 = (float)(short)((meta >> 48) & 0xFFFFu);
    float ca = fmaxf(cx2 - cx1, 0.f) * fmaxf(cy2 - cy1, 0.f);

    bool supp = false;
#pragma unroll
    for (int r = 0; r < 2; ++r) {
        int slot = lane + 64 * r;
        if (slot < nk && K.cl[r] == cls) {
            float ix1 = fmaxf(K.x1[r], cx1), iy1 = fmaxf(K.y1[r], cy1);
            float ix2 = fminf(K.x2[r], cx2), iy2 = fminf(K.y2[r], cy2);
            float inter = fmaxf(ix2 - ix1, 0.f) * fmaxf(iy2 - iy1, 0.f);
            if (3.f * inter > K.ar[r] + ca) supp = true;   // exact iou>0.5 (ints exact in f32)
        }
    }
    if (__ballot(supp) != 0ULL) return;

    int rr = nk >> 6, l = nk & 63;
    if (lane == l) {
        if (rr == 0) { K.x1[0]=cx1; K.y1[0]=cy1; K.x2[0]=cx2; K.y2[0]=cy2; K.ar[0]=ca; K.cl[0]=cls; }
        else         { K.x1[1]=cx1; K.y1[1]=cy1; K.x2[1]=cx2; K.y2[1]=cy2; K.ar[1]=ca; K.cl[1]=cls; }
    }
    if (lane == 0) {
        out[b * MAXDET + nk] = s;
        out[2 * MAXDET + b * MAXDET + nk] = (float)cls;
        float* ob = out + 4 * MAXDET + (size_t)(b * MAXDET + nk) * 4;
        ob[0] = cx1; ob[1] = cy1; ob[2] = cx2; ob[3] = cy2;
    }
    ++nk;
}

// ---------------- Phase-B sort-256: template recursion => all indices compile-time ----------------
// (rule #20: runtime-indexed per-thread arrays go to scratch; this guarantees VGPR residency)
template<int K, int J>
__device__ __forceinline__ void sB(uint64_t (&k4)[4], uint64_t (&m4)[4], int lane) {
    if constexpr (J >= 64) {
        constexpr int d = J >> 6;
#pragma unroll
        for (int i = 0; i < 4; ++i) {
            if ((i & d) == 0) {
                constexpr int dd = d;
                const int ih = i | dd;           // compile-time after unroll
                int p = i * 64 + lane;
                bool ilmin = ((p & K) != 0);     // direction for lower-index element
                bool sw = ilmin ? (k4[i] > k4[ih]) : (k4[i] < k4[ih]);
                if (sw) {
                    uint64_t tk = k4[i]; k4[i] = k4[ih]; k4[ih] = tk;
                    uint64_t tm = m4[i]; m4[i] = m4[ih]; m4[ih] = tm;
                }
            }
        }
    } else {
#pragma unroll
        for (int i = 0; i < 4; ++i) {
            int p = i * 64 + lane;
            uint64_t ok = __shfl_xor(k4[i], J);
            uint64_t om = __shfl_xor(m4[i], J);
            bool keepmin = (((p & K) != 0) == ((lane & J) == 0));
            bool take = keepmin ? (ok < k4[i]) : (ok > k4[i]);
            if (take) { k4[i] = ok; m4[i] = om; }
        }
    }
    if constexpr (J > 1) sB<K, (J >> 1)>(k4, m4, lane);
}

template<int K>
__device__ __forceinline__ void rB(uint64_t (&k4)[4], uint64_t (&m4)[4], int lane) {
    sB<K, (K >> 1)>(k4, m4, lane);
    if constexpr (K < NSEL) rB<(K << 1)>(k4, m4, lane);
}

// ---------------- Kernel 2: 2-level select + register sort + batched NMS ----------------
__global__ __launch_bounds__(1024)
void sort_nms_kernel(const uint64_t* __restrict__ ws, float* __restrict__ out) {
    __shared__ __align__(16) uint64_t sp[2 * NRUN * 64];   // 16 sorted runs of 64 (key,meta)
    __shared__ __align__(16) uint64_t sq[2 * NSEL];        // sorted 256 for NMS
    __shared__ uint64_t karr[NCHUNK];
    __shared__ float4 kept_box[MAXDET];
    __shared__ float  kept_area[MAXDET];
    __shared__ int    kept_cls[MAXDET];
    __shared__ float4 sbox[64];                            // per-batch staged unpack
    __shared__ float  sarea[64];
    __shared__ int    scls[64];

    const int b = blockIdx.x;
    const int tid = threadIdx.x;
    const int w = tid >> 6;
    const int lane = tid & 63;
    const uint64_t* g = ws + (size_t)b * NCHUNK * 64 * 2;

    // ---- Phase A: each wave register-sorts its 64 staged entries (top-8 of 8 chunks) ----
    {
        int chunk = w * 8 + (lane >> 3), rank = lane & 7;
        size_t e = (size_t)chunk * 64 + rank;
        ulonglong2 v = *reinterpret_cast<const ulonglong2*>(&g[2 * e]);
        uint64_t rk = v.x, rm = v.y;
        if (tid < NCHUNK) karr[tid] = g[2 * ((size_t)tid * 64 + STAGE_R)];  // 9th-best per chunk

#pragma unroll
        for (int k = 2; k <= 64; k <<= 1) {
#pragma unroll
            for (int j = k >> 1; j > 0; j >>= 1) {
                uint64_t ok = __shfl_xor(rk, j);
                uint64_t om = __shfl_xor(rm, j);
                bool keepmin = (((lane & k) != 0) == ((lane & j) == 0));
                bool take = keepmin ? (ok < rk) : (ok > rk);
                if (take) { rk = ok; rm = om; }
            }
        }
        *reinterpret_cast<ulonglong2*>(&sp[2 * (w * 64 + lane)]) = make_ulonglong2(rk, rm);
    }
    __syncthreads();

    if (tid >= 64) return;

    // ---- wave 0 from here on ----
    // guard: kstar = max(9th of each chunk, 17th of each run)
    uint64_t kstar;
    {
        uint64_t m = karr[lane] > karr[lane + 64] ? karr[lane] : karr[lane + 64];
        uint64_t m2 = (lane < NRUN) ? sp[2 * (lane * 64 + 16)] : 0ULL;
        if (m2 > m) m = m2;
#pragma unroll
        for (int j = 32; j; j >>= 1) {
            uint64_t o = __shfl_xor(m, j);
            if (o > m) m = o;
        }
        kstar = m;
    }

    // load top-16 of each run; odd blocks reversed => 16-blocks alternate desc/asc,
    // so the bitonic network can start at k=32 (first 10 stages skipped)
    uint64_t k4[4], m4[4];
#pragma unroll
    for (int i = 0; i < 4; ++i) {
        int p = i * 64 + lane;
        int m = p >> 4;
        int r = (m & 1) ? (15 - (p & 15)) : (p & 15);
        ulonglong2 v = *reinterpret_cast<const ulonglong2*>(&sp[2 * (m * 64 + r)]);
        k4[i] = v.x; m4[i] = v.y;
    }

    rB<32>(k4, m4, lane);   // fully-unrolled bitonic k=32..256, descending

#pragma unroll
    for (int i = 0; i < 4; ++i)
        *reinterpret_cast<ulonglong2*>(&sq[2 * (i * 64 + lane)]) = make_ulonglong2(k4[i], m4[i]);
    __builtin_amdgcn_wave_barrier();

    // ---- batched greedy NMS over sorted 256 ----
    int nk = 0;
    bool need_fb = false;
    bool done = false;

    for (int p0 = 0; p0 < NSEL && !done; p0 += 64) {
        ulonglong2 kv = *reinterpret_cast<const ulonglong2*>(&sq[2 * (p0 + lane)]);
        uint64_t key = kv.x, meta = kv.y;
        float s = key_score(key);
        bool sval = (s > SCORE_TH);
        bool trusted = (key > kstar);
        int cls_c = sval ? (int)(key & 0xFFFFu) : -1;       // sentinel: never matches
        float cx1 = (float)(short)(meta & 0xFFFFu);
        float cy1 = (float)(short)((meta >> 16) & 0xFFFFu);
        float cx2 = (float)(short)((meta >> 32) & 0xFFFFu);
        float cy2 = (float)(short)((meta >> 48) & 0xFFFFu);
        float ca = fmaxf(cx2 - cx1, 0.f) * fmaxf(cy2 - cy1, 0.f);

        // stage unpacked candidate fields (single wave: program order + in-order LDS pipe)
        sbox[lane]  = make_float4(cx1, cy1, cx2, cy2);
        sarea[lane] = ca;
        scls[lane]  = sval ? (int)(key & 0xFFFFu) : 0x7FFF;  // sentinel: never matches
        __builtin_amdgcn_wave_barrier();

        // vs previously-kept set
        bool supk = false;
        for (int j = 0; j < nk; ++j) {
            float4 kb = kept_box[j];
            float ix1 = fmaxf(kb.x, cx1), iy1 = fmaxf(kb.y, cy1);
            float ix2 = fminf(kb.z, cx2), iy2 = fminf(kb.w, cy2);
            float inter = fmaxf(ix2 - ix1, 0.f) * fmaxf(iy2 - iy1, 0.f);
            supk |= (kept_cls[j] == cls_c) & (3.f * inter > kept_area[j] + ca);
        }
        bool alive0 = sval && trusted && !supk;

        // intra-batch pairwise suppression mask (staged LDS broadcast reads)
        uint64_t supBy = 0;
#pragma unroll 4
        for (int t = 0; t < 64; ++t) {
            float4 tb = sbox[t];
            float ta = sarea[t];
            int tcls = scls[t];
            float ix1 = fmaxf(tb.x, cx1), iy1 = fmaxf(tb.y, cy1);
            float ix2 = fminf(tb.z, cx2), iy2 = fminf(tb.w, cy2);
            float inter = fmaxf(ix2 - ix1, 0.f) * fmaxf(iy2 - iy1, 0.f);
            bool sup = (t < lane) && (tcls == cls_c) && (3.f * inter > ta + ca);
            supBy |= ((uint64_t)sup) << t;
        }

        uint64_t aliveCand = __ballot(alive0);
        uint64_t aliveMask;
        if (__ballot(supBy != 0ULL) == 0ULL) {
            aliveMask = aliveCand;          // fast path: no intra-batch suppression at all
        } else {
            uint64_t killed = 0;
            for (int t = 0; t < 64; ++t) {
                uint64_t kill_t = __ballot((supBy >> t) & 1ULL);
                bool talive = ((aliveCand >> t) & 1ULL) && !((killed >> t) & 1ULL);
                if (talive) killed |= kill_t;
            }
            aliveMask = aliveCand & ~killed;
        }

        int myrank = __popcll(aliveMask & ((1ULL << lane) - 1ULL));
        bool keepme = ((aliveMask >> lane) & 1ULL) && (nk + myrank < MAXDET);
        if (keepme) {
            int slot = nk + myrank;
            kept_box[slot]  = make_float4(cx1, cy1, cx2, cy2);
            kept_area[slot] = ca;
            kept_cls[slot]  = cls_c;
            out[b * MAXDET + slot] = s;
            out[2 * MAXDET + b * MAXDET + slot] = (float)cls_c;
            float* ob = out + 4 * MAXDET + (size_t)(b * MAXDET + slot) * 4;
            ob[0] = cx1; ob[1] = cy1; ob[2] = cx2; ob[3] = cy2;
        }
        int navail = __popcll(aliveMask);
        int room = MAXDET - nk;
        nk += (navail < room) ? navail : room;

        uint64_t guardFail = __ballot(sval && !trusted);
        uint64_t invalid   = __ballot(!sval);
        if (nk >= MAXDET) done = true;
        else if (guardFail) { need_fb = true; done = true; }
        else if (invalid) done = true;
    }
    if (!done && nk < MAXDET) need_fb = true;   // exhausted selected set

    // ---- cold exact fallback: 128-stream merge over full sorted chunks ----
    if (need_fb) {
        nk = 0;
        Kept K;
        K.cl[0] = K.cl[1] = -1;
        K.x1[0]=K.y1[0]=K.x2[0]=K.y2[0]=K.ar[0]=0.f;
        K.x1[1]=K.y1[1]=K.x2[1]=K.y2[1]=K.ar[1]=0.f;
        int p0 = 0, p1 = 0;
        uint64_t h0k = g[2 * ((size_t)lane * 64)];
        uint64_t h0m = g[2 * ((size_t)lane * 64) + 1];
        uint64_t h1k = g[2 * ((size_t)(lane + 64) * 64)];
        uint64_t h1m = g[2 * ((size_t)(lane + 64) * 64) + 1];
        while (true) {
            uint64_t mk = (h0k > h1k) ? h0k : h1k;
            uint64_t r = mk;
#pragma unroll
            for (int j = 32; j; j >>= 1) {
                uint64_t o = __shfl_xor(r, j);
                if (o > r) r = o;
            }
            if (r == 0ULL) break;
            float s = key_score(r);
            if (!(s > SCORE_TH)) break;
            uint64_t wmask = __ballot(mk == r);
            int wl = __ffsll((unsigned long long)wmask) - 1;
            uint64_t mym = (h0k > h1k) ? h0m : h1m;
            uint64_t cm = __shfl(mym, wl);
            nms_try_keep(r, cm, s, lane, nk, K, out, b);
            if (nk == MAXDET) break;
            if (lane == wl) {
                if (h0k > h1k) {
                    ++p0; bool v = p0 < 64;
                    h0k = v ? g[2 * ((size_t)lane * 64 + p0)] : 0ULL;
                    h0m = v ? g[2 * ((size_t)lane * 64 + p0) + 1] : 0ULL;
                } else {
                    ++p1; bool v = p1 < 64;
                    h1k = v ? g[2 * ((size_t)(lane + 64) * 64 + p1)] : 0ULL;
                    h1m = v ? g[2 * ((size_t)(lane + 64) * 64 + p1) + 1] : 0ULL;
                }
            }
        }
    }

    // pad remaining slots with -1
    for (int t = nk + lane; t < MAXDET; t += 64) {
        out[b * MAXDET + t] = -1.f;
        out[2 * MAXDET + b * MAXDET + t] = -1.f;
        float* ob = out + 4 * MAXDET + (size_t)(b * MAXDET + t) * 4;
        ob[0] = -1.f; ob[1] = -1.f; ob[2] = -1.f; ob[3] = -1.f;
    }
}

extern "C" void kernel_launch(void* const* d_in, const int* in_sizes, int n_in,
                              void* d_out, int out_size, void* d_ws, size_t ws_size,
                              hipStream_t stream) {
    (void)in_sizes; (void)n_in; (void)out_size; (void)ws_size;
    const float* cls_heads = (const float*)d_in[0];
    const float* reg_heads = (const float*)d_in[1];
    const float* anchors   = (const float*)d_in[2];
    float* out = (float*)d_out;
    uint64_t* ws = (uint64_t*)d_ws;   // 2 batches x 128 chunks x 64 x (key,meta) = 256 KiB

    decode_sort_kernel<<<dim3(NCHUNK, 2), 64, 0, stream>>>(cls_heads, reg_heads, anchors, ws);
    sort_nms_kernel<<<dim3(2), 1024, 0, stream>>>(ws, out);
}